// Round 9
// baseline (266.235 us; speedup 1.0000x reference)
//
#include <hip/hip_runtime.h>
#include <stdint.h>

#define BTOT 512
#define SQLEN 512
#define TTAB 20
#define EMB 32
#define DDIM 322            // E*10+2
#define KP 352              // padded K (11*32)
#define NP 384              // padded N (24*16) -> 6 frags per wave, 4 waves
#define MBLK 64             // rows per block
#define NFRAG 24            // total 16-wide N fragments

typedef __attribute__((ext_vector_type(4))) float f32x4;
typedef __attribute__((ext_vector_type(8))) __bf16 bf16x8;

static __device__ __forceinline__ unsigned short f2bf(float f) {
    unsigned int u = __float_as_uint(f);
    u += 0x7fffu + ((u >> 16) & 1u);   // round-to-nearest-even
    return (unsigned short)(u >> 16);
}

// pack 8 f32 -> bf16x8 (compiler emits v_cvt_pk_bf16_f32 pairs)
static __device__ __forceinline__ bf16x8 pk8(float4 u0, float4 u1) {
    bf16x8 r;
    r[0] = (__bf16)u0.x; r[1] = (__bf16)u0.y; r[2] = (__bf16)u0.z; r[3] = (__bf16)u0.w;
    r[4] = (__bf16)u1.x; r[5] = (__bf16)u1.y; r[6] = (__bf16)u1.z; r[7] = (__bf16)u1.w;
    return r;
}

// W [322][322] f32 (o x d) -> wb2 bf16 fragments in MFMA lane order.
// (n,k) -> frag ((k>>5)*24 + (n>>4)), lane ((n&15) | (((k>>3)&3)<<4)), e (k&7)
__global__ void prep_w(const float* __restrict__ W, unsigned short* __restrict__ wb2) {
    int idx = blockIdx.x * 256 + threadIdx.x;
    if (idx >= NP * KP) return;
    int n = idx / KP;
    int k = idx - n * KP;
    float v = (n < DDIM && k < DDIM) ? W[n * DDIM + k] : 0.0f;
    int dst = ((k >> 5) * NFRAG + (n >> 4)) * 512
            + ((n & 15) + (((k >> 3) & 3) << 4)) * 8 + (k & 7);
    wb2[dst] = f2bf(v);
}

__global__ __launch_bounds__(256, 2) void fused_embed_gemm(
    const float* __restrict__ feature,       // [BT*SQ][12]
    const float* __restrict__ join_tables,   // [BT][20][32]
    const float* __restrict__ type_embed,    // [32][32]
    const float* __restrict__ column_embed,  // [300][32]
    const unsigned short* __restrict__ wb2,  // permuted bf16 W fragments
    const float* __restrict__ bias,          // [322]
    float* __restrict__ out)                 // [BT*SQ][322] f32
{
    __shared__ float F_lds[MBLK * 12];       // 3 KB: ids+costs for the 64 rows

    const int t = threadIdx.x;
    const long mbase = (long)blockIdx.x * MBLK;
    const int b = (int)(mbase >> 9);         // 64 | 512 => one batch per block

    {
        const float* src = feature + mbase * 12;
        #pragma unroll
        for (int i = 0; i < 3; ++i) F_lds[i * 256 + t] = src[i * 256 + t];
    }
    __syncthreads();                          // the ONLY barrier

    const int lane = t & 63;
    const int wn   = t >> 6;                  // wave owns N-frags wn*6..wn*6+5
    const int l15  = lane & 15;
    const int lq   = lane >> 4;

    const float* jtb = join_tables + (long)b * (TTAB * EMB);

    f32x4 acc[4][6];
    #pragma unroll
    for (int mf = 0; mf < 4; ++mf)
        #pragma unroll
        for (int nf = 0; nf < 6; ++nf)
            acc[mf][nf] = (f32x4){0.f, 0.f, 0.f, 0.f};

    const unsigned short* bbase = wb2 + ((long)(wn * 6) * 512) + lane * 8;

    bf16x8 b0[6], b1[6], A0[4], A1[4];

#define LOAD_B(bank, ksl)                                                        \
    _Pragma("unroll")                                                            \
    for (int nf = 0; nf < 6; ++nf)                                               \
        bank[nf] = *reinterpret_cast<const bf16x8*>(bbase + (long)((ksl) * NFRAG + nf) * 512);

    // A-fragment direct from embedding tables: chunk c == ks (32-aligned).
#define LOAD_A(bank, ksl) {                                                      \
    _Pragma("unroll")                                                            \
    for (int mf = 0; mf < 4; ++mf) {                                             \
        const int row = mf * 16 + l15;                                           \
        if ((ksl) < 10) {                                                        \
            const int id = (int)F_lds[row * 12 + (ksl)];                         \
            const float* basep;                                                  \
            bool nz;                                                             \
            if ((ksl) == 0)      { basep = type_embed;   nz = true;  }           \
            else if ((ksl) == 1 || ((ksl) >= 4 && (ksl) <= 6))                   \
                                 { basep = jtb;          nz = false; }           \
            else                 { basep = column_embed; nz = true;  }           \
            const float* ap = basep + id * EMB + lq * 8;                         \
            float4 u0 = make_float4(0.f,0.f,0.f,0.f);                            \
            float4 u1 = make_float4(0.f,0.f,0.f,0.f);                            \
            if (!nz || id != 0) {                                                \
                u0 = *reinterpret_cast<const float4*>(ap);                       \
                u1 = *reinterpret_cast<const float4*>(ap + 4);                   \
            }                                                                    \
            bank[mf] = pk8(u0, u1);                                              \
        } else {                                                                 \
            bf16x8 a;                                                            \
            _Pragma("unroll")                                                    \
            for (int e = 0; e < 8; ++e) a[e] = (__bf16)0.0f;                     \
            if (lq == 0) {                                                       \
                a[0] = (__bf16)F_lds[row * 12 + 10];                             \
                a[1] = (__bf16)F_lds[row * 12 + 11];                             \
            }                                                                    \
            bank[mf] = a;                                                        \
        }                                                                        \
    } }

#define GEMM_STEP(bb, aa)                                                        \
    _Pragma("unroll")                                                            \
    for (int nf = 0; nf < 6; ++nf) {                                             \
        acc[0][nf] = __builtin_amdgcn_mfma_f32_16x16x32_bf16(aa[0], bb[nf], acc[0][nf], 0, 0, 0); \
        acc[1][nf] = __builtin_amdgcn_mfma_f32_16x16x32_bf16(aa[1], bb[nf], acc[1][nf], 0, 0, 0); \
        acc[2][nf] = __builtin_amdgcn_mfma_f32_16x16x32_bf16(aa[2], bb[nf], acc[2][nf], 0, 0, 0); \
        acc[3][nf] = __builtin_amdgcn_mfma_f32_16x16x32_bf16(aa[3], bb[nf], acc[3][nf], 0, 0, 0); \
    }

    LOAD_B(b0, 0);
    LOAD_A(A0, 0);
    #pragma unroll
    for (int kp = 0; kp < 5; ++kp) {
        const int ks = kp * 2;
        LOAD_B(b1, ks + 1);
        LOAD_A(A1, ks + 1);
        GEMM_STEP(b0, A0);
        LOAD_B(b0, ks + 2);
        LOAD_A(A0, ks + 2);
        GEMM_STEP(b1, A1);
    }
    GEMM_STEP(b0, A0);                        // ks = 10

    // ---- epilogue: +bias, leaky_relu, store f32 (drop padded cols) ----
    #pragma unroll
    for (int nf = 0; nf < 6; ++nf) {
        int col = wn * 96 + nf * 16 + l15;
        if (col < DDIM) {
            float bv = bias[col];
            #pragma unroll
            for (int mf = 0; mf < 4; ++mf) {
                long rbase = mbase + mf * 16 + lq * 4;
                #pragma unroll
                for (int r = 0; r < 4; ++r) {
                    float x = acc[mf][nf][r] + bv;
                    x = (x > 0.f) ? x : 0.01f * x;
                    out[(rbase + r) * DDIM + col] = x;
                }
            }
        }
    }
}

extern "C" void kernel_launch(void* const* d_in, const int* in_sizes, int n_in,
                              void* d_out, int out_size, void* d_ws, size_t ws_size,
                              hipStream_t stream) {
    const float* feature      = (const float*)d_in[0];
    const float* join_tables  = (const float*)d_in[1];
    const float* type_embed   = (const float*)d_in[2];
    const float* column_embed = (const float*)d_in[3];
    const float* W            = (const float*)d_in[4];
    const float* bias         = (const float*)d_in[5];
    float* out = (float*)d_out;
    unsigned short* wb2 = (unsigned short*)d_ws;   // 11*24*512*2 = 270 KB

    hipLaunchKernelGGL(prep_w, dim3((NP * KP + 255) / 256), dim3(256), 0, stream, W, wb2);

    const int nblocks = (BTOT * SQLEN) / MBLK;    // 4096
    hipLaunchKernelGGL(fused_embed_gemm, dim3(nblocks), dim3(256), 0, stream,
                       feature, join_tables, type_embed, column_embed, wb2, bias, out);
}

// Round 11
// 154.880 us; speedup vs baseline: 1.7190x; 1.7190x over previous
//
#include <hip/hip_runtime.h>
#include <stdint.h>

#define BTOT 512
#define SQLEN 512
#define TTAB 20
#define EMB 32
#define DDIM 322            // E*10+2
#define KP 352              // padded K (11*32)
#define NP 384              // padded N (24*16) -> 6 frags per wave, 4 waves
#define MBLK 64             // rows per block
#define LDA 360             // A_lds row stride in bf16 elems (720B)
#define NFRAG 24            // total 16-wide N fragments

typedef __attribute__((ext_vector_type(4))) float f32x4;
typedef __attribute__((ext_vector_type(8))) __bf16 bf16x8;

static __device__ __forceinline__ unsigned short f2bf(float f) {
    unsigned int u = __float_as_uint(f);
    u += 0x7fffu + ((u >> 16) & 1u);   // round-to-nearest-even
    return (unsigned short)(u >> 16);
}

// W [322][322] f32 (o x d) -> wb2 bf16 fragments in MFMA lane order.
// (n,k) -> frag ((k>>5)*24 + (n>>4)), lane ((n&15) | (((k>>3)&3)<<4)), e (k&7)
// A wave's B-fragment load = wb2 + frag*512 + lane*8 : contiguous 1KB.
__global__ void prep_w(const float* __restrict__ W, unsigned short* __restrict__ wb2) {
    int idx = blockIdx.x * 256 + threadIdx.x;
    if (idx >= NP * KP) return;
    int n = idx / KP;
    int k = idx - n * KP;
    float v = (n < DDIM && k < DDIM) ? W[n * DDIM + k] : 0.0f;
    int dst = ((k >> 5) * NFRAG + (n >> 4)) * 512
            + ((n & 15) + (((k >> 3) & 3) << 4)) * 8 + (k & 7);
    wb2[dst] = f2bf(v);
}

__global__ __launch_bounds__(256, 2) void fused_embed_gemm(
    const float* __restrict__ feature,       // [BT*SQ][12]
    const float* __restrict__ join_tables,   // [BT][20][32]
    const float* __restrict__ type_embed,    // [32][32]
    const float* __restrict__ column_embed,  // [300][32]
    const unsigned short* __restrict__ wb2,  // permuted bf16 W fragments
    const float* __restrict__ bias,          // [322]
    float* __restrict__ out)                 // [BT*SQ][322] f32
{
    __shared__ __align__(16) unsigned short A_lds[MBLK * LDA];  // 45 KB (reused by epilogue)
    __shared__ float F_lds[MBLK * 12];                          // 3 KB

    const int t = threadIdx.x;
    const long mbase = (long)blockIdx.x * MBLK;
    const int b = (int)(mbase >> 9);   // 64 | 512 => whole block in one batch

    // ---- stage the 64 feature rows ----
    {
        const float* src = feature + mbase * 12;
        #pragma unroll
        for (int i = 0; i < 3; ++i) {
            int off = i * 256 + t;
            F_lds[off] = src[off];
        }
    }
    __syncthreads();

    // ---- gather embeddings into A_lds as bf16, float4 per iter ----
    const float* jtb = join_tables + (long)b * (TTAB * EMB);
    #pragma unroll 4
    for (int i = 0; i < 20; ++i) {              // 64 rows * 80 quads / 256 thr
        int pidx = i * 256 + t;
        int row = pidx / 80;
        int q = pidx - row * 80;
        int d = q << 2;
        int c = q >> 3;
        int j = d & 31;
        float4 v = make_float4(0.f, 0.f, 0.f, 0.f);
        int id = (int)F_lds[row * 12 + c];
        const float* src;
        bool nz = true;
        if (c == 0)                            { src = type_embed + id * EMB;  nz = (id != 0); }
        else if (c == 1 || (c >= 4 && c <= 6)) { src = jtb + id * EMB; }
        else                                   { src = column_embed + id * EMB; nz = (id != 0); }
        if (nz) v = *reinterpret_cast<const float4*>(src + j);
        uint2 pk;
        pk.x = (unsigned int)f2bf(v.x) | ((unsigned int)f2bf(v.y) << 16);
        pk.y = (unsigned int)f2bf(v.z) | ((unsigned int)f2bf(v.w) << 16);
        *reinterpret_cast<uint2*>(&A_lds[row * LDA + d]) = pk;
    }
    // ---- cost pair + zero pad: d in [320,360) ----
    #pragma unroll
    for (int i = 0; i < 3; ++i) {
        int pidx = i * 256 + t;
        if (pidx < 640) {
            int row = pidx / 10;
            int gi = pidx - row * 10;
            int d = 320 + (gi << 2);
            uint2 pk = make_uint2(0u, 0u);
            if (gi == 0) {
                pk.x = (unsigned int)f2bf(F_lds[row * 12 + 10])
                     | ((unsigned int)f2bf(F_lds[row * 12 + 11]) << 16);
            }
            *reinterpret_cast<uint2*>(&A_lds[row * LDA + d]) = pk;
        }
    }
    __syncthreads();

    // ---- MFMA GEMM: 4 waves as 1M x 4N, wave tile 64 x 96, reg-dbuf B ----
    const int lane = t & 63;
    const int wn   = t >> 6;          // wave owns frags wn*6 .. wn*6+5
    const int l15  = lane & 15;
    const int lq   = lane >> 4;

    f32x4 acc[4][6];
    #pragma unroll
    for (int mf = 0; mf < 4; ++mf)
        #pragma unroll
        for (int nf = 0; nf < 6; ++nf)
            acc[mf][nf] = (f32x4){0.f, 0.f, 0.f, 0.f};

    const int arow0 = l15 * LDA + lq * 8;
    const unsigned short* bbase = wb2 + ((long)(wn * 6) * 512) + lane * 8;

    bf16x8 b0[6], b1[6];

#define LOAD_B(bank, ksl)                                                        \
    _Pragma("unroll")                                                            \
    for (int nf = 0; nf < 6; ++nf)                                               \
        bank[nf] = *reinterpret_cast<const bf16x8*>(bbase + (long)((ksl) * NFRAG + nf) * 512);

#define GEMM_STEP(bank, ksl) {                                                   \
    bf16x8 a0 = *reinterpret_cast<const bf16x8*>(&A_lds[arow0 + (ksl) * 32]);    \
    bf16x8 a1 = *reinterpret_cast<const bf16x8*>(&A_lds[arow0 + 16 * LDA + (ksl) * 32]); \
    bf16x8 a2 = *reinterpret_cast<const bf16x8*>(&A_lds[arow0 + 32 * LDA + (ksl) * 32]); \
    bf16x8 a3 = *reinterpret_cast<const bf16x8*>(&A_lds[arow0 + 48 * LDA + (ksl) * 32]); \
    _Pragma("unroll")                                                            \
    for (int nf = 0; nf < 6; ++nf) {                                             \
        acc[0][nf] = __builtin_amdgcn_mfma_f32_16x16x32_bf16(a0, bank[nf], acc[0][nf], 0, 0, 0); \
        acc[1][nf] = __builtin_amdgcn_mfma_f32_16x16x32_bf16(a1, bank[nf], acc[1][nf], 0, 0, 0); \
        acc[2][nf] = __builtin_amdgcn_mfma_f32_16x16x32_bf16(a2, bank[nf], acc[2][nf], 0, 0, 0); \
        acc[3][nf] = __builtin_amdgcn_mfma_f32_16x16x32_bf16(a3, bank[nf], acc[3][nf], 0, 0, 0); \
    } }

    LOAD_B(b0, 0);
    #pragma unroll
    for (int kp = 0; kp < 5; ++kp) {
        const int ks = kp * 2;
        LOAD_B(b1, ks + 1);
        GEMM_STEP(b0, ks);
        LOAD_B(b0, ks + 2);
        GEMM_STEP(b1, ks + 1);
    }
    GEMM_STEP(b0, 10);

    // ---- epilogue: +bias, leaky_relu; LDS transpose -> contiguous nt f32x4 ----
    float bv[6];
    #pragma unroll
    for (int nf = 0; nf < 6; ++nf) {
        int col = wn * 96 + nf * 16 + l15;
        bv[nf] = (col < DDIM) ? bias[col] : 0.f;
    }

    float* T_lds = reinterpret_cast<float*>(A_lds);         // 16*322*4 = 20.6 KB < 45 KB
    float* outp = out + mbase * DDIM;
    const int CH4 = 16 * DDIM / 4;                          // 1288 f32x4 per 16-row chunk

    #pragma unroll
    for (int mf = 0; mf < 4; ++mf) {
        __syncthreads();                                    // A_lds / prev chunk reads done
        #pragma unroll
        for (int nf = 0; nf < 6; ++nf) {
            int col = wn * 96 + nf * 16 + l15;
            if (col < DDIM) {
                #pragma unroll
                for (int r = 0; r < 4; ++r) {
                    float x = acc[mf][nf][r] + bv[nf];
                    x = (x > 0.f) ? x : 0.01f * x;
                    T_lds[(lq * 4 + r) * DDIM + col] = x;
                }
            }
        }
        __syncthreads();
        #pragma unroll
        for (int i = 0; i < 6; ++i) {
            int fid = i * 256 + t;
            if (fid < CH4) {
                f32x4 v = *reinterpret_cast<const f32x4*>(&T_lds[fid * 4]);
                __builtin_nontemporal_store(v,
                    reinterpret_cast<f32x4*>(outp + ((long)mf * CH4 + fid) * 4));
            }
        }
    }
}

extern "C" void kernel_launch(void* const* d_in, const int* in_sizes, int n_in,
                              void* d_out, int out_size, void* d_ws, size_t ws_size,
                              hipStream_t stream) {
    const float* feature      = (const float*)d_in[0];
    const float* join_tables  = (const float*)d_in[1];
    const float* type_embed   = (const float*)d_in[2];
    const float* column_embed = (const float*)d_in[3];
    const float* W            = (const float*)d_in[4];
    const float* bias         = (const float*)d_in[5];
    float* out = (float*)d_out;
    unsigned short* wb2 = (unsigned short*)d_ws;   // 11*24*512*2 = 270 KB

    hipLaunchKernelGGL(prep_w, dim3((NP * KP + 255) / 256), dim3(256), 0, stream, W, wb2);

    const int nblocks = (BTOT * SQLEN) / MBLK;    // 4096
    hipLaunchKernelGGL(fused_embed_gemm, dim3(nblocks), dim3(256), 0, stream,
                       feature, join_tables, type_embed, column_embed, wb2, bias, out);
}

// Round 13
// 128.741 us; speedup vs baseline: 2.0680x; 1.2030x over previous
//
#include <hip/hip_runtime.h>
#include <stdint.h>

#define BTOT 512
#define SQLEN 512
#define TTAB 20
#define EMB 32
#define DDIM 322            // E*10+2
#define KP 352              // padded K (11*32)
#define NP 384              // padded N (24*16) -> 6 frags per wave, 4 waves
#define MBLK 64             // rows per block
#define LDA 360             // A_lds row stride in bf16 elems (720B)
#define NFRAG 24            // total 16-wide N fragments

typedef __attribute__((ext_vector_type(4))) float f32x4;
typedef __attribute__((ext_vector_type(8))) __bf16 bf16x8;

static __device__ __forceinline__ unsigned short f2bf(float f) {
    unsigned int u = __float_as_uint(f);
    u += 0x7fffu + ((u >> 16) & 1u);   // round-to-nearest-even
    return (unsigned short)(u >> 16);
}

// W [322][322] f32 (o x d) -> wb2 bf16 fragments in MFMA lane order.
// (n,k) -> frag ((k>>5)*24 + (n>>4)), lane ((n&15) | (((k>>3)&3)<<4)), e (k&7)
// A wave's B-fragment load = wb2 + frag*512 + lane*8 : contiguous 1KB.
__global__ void prep_w(const float* __restrict__ W, unsigned short* __restrict__ wb2) {
    int idx = blockIdx.x * 256 + threadIdx.x;
    if (idx >= NP * KP) return;
    int n = idx / KP;
    int k = idx - n * KP;
    float v = (n < DDIM && k < DDIM) ? W[n * DDIM + k] : 0.0f;
    int dst = ((k >> 5) * NFRAG + (n >> 4)) * 512
            + ((n & 15) + (((k >> 3) & 3) << 4)) * 8 + (k & 7);
    wb2[dst] = f2bf(v);
}

__global__ __launch_bounds__(256, 3) void fused_embed_gemm(
    const float* __restrict__ feature,       // [BT*SQ][12]
    const float* __restrict__ join_tables,   // [BT][20][32]
    const float* __restrict__ type_embed,    // [32][32]
    const float* __restrict__ column_embed,  // [300][32]
    const unsigned short* __restrict__ wb2,  // permuted bf16 W fragments
    const float* __restrict__ bias,          // [322]
    float* __restrict__ out)                 // [BT*SQ][322] f32
{
    __shared__ __align__(16) unsigned short A_lds[MBLK * LDA];  // 45 KB (reused by epilogue)
    __shared__ float F_lds[MBLK * 12];                          // 3 KB

    const int t = threadIdx.x;
    const long mbase = (long)blockIdx.x * MBLK;
    const int b = (int)(mbase >> 9);   // 64 | 512 => whole block in one batch

    const int lane = t & 63;
    const int wn   = t >> 6;          // wave owns frags wn*6 .. wn*6+5
    const int l15  = lane & 15;
    const int lq   = lane >> 4;
    const unsigned short* bbase = wb2 + ((long)(wn * 6) * 512) + lane * 8;

    bf16x8 b0[6], b1[6];

#define LOAD_B(bank, ksl)                                                        \
    _Pragma("unroll")                                                            \
    for (int nf = 0; nf < 6; ++nf)                                               \
        bank[nf] = *reinterpret_cast<const bf16x8*>(bbase + (long)((ksl) * NFRAG + nf) * 512);

    // ---- stage the 64 feature rows ----
    {
        const float* src = feature + mbase * 12;
        #pragma unroll
        for (int i = 0; i < 3; ++i) {
            int off = i * 256 + t;
            F_lds[off] = src[off];
        }
    }
    __syncthreads();

    // ---- gather embeddings into A_lds as bf16, float4 per iter ----
    const float* jtb = join_tables + (long)b * (TTAB * EMB);
    #pragma unroll 4
    for (int i = 0; i < 20; ++i) {              // 64 rows * 80 quads / 256 thr
        int pidx = i * 256 + t;
        int row = pidx / 80;
        int q = pidx - row * 80;
        int d = q << 2;
        int c = q >> 3;
        int j = d & 31;
        float4 v = make_float4(0.f, 0.f, 0.f, 0.f);
        int id = (int)F_lds[row * 12 + c];
        const float* src;
        bool nz = true;
        if (c == 0)                            { src = type_embed + id * EMB;  nz = (id != 0); }
        else if (c == 1 || (c >= 4 && c <= 6)) { src = jtb + id * EMB; }
        else                                   { src = column_embed + id * EMB; nz = (id != 0); }
        if (nz) v = *reinterpret_cast<const float4*>(src + j);
        uint2 pk;
        pk.x = (unsigned int)f2bf(v.x) | ((unsigned int)f2bf(v.y) << 16);
        pk.y = (unsigned int)f2bf(v.z) | ((unsigned int)f2bf(v.w) << 16);
        *reinterpret_cast<uint2*>(&A_lds[row * LDA + d]) = pk;
    }
    // ---- cost pair + zero pad: d in [320,360) ----
    #pragma unroll
    for (int i = 0; i < 3; ++i) {
        int pidx = i * 256 + t;
        if (pidx < 640) {
            int row = pidx / 10;
            int gi = pidx - row * 10;
            int d = 320 + (gi << 2);
            uint2 pk = make_uint2(0u, 0u);
            if (gi == 0) {
                pk.x = (unsigned int)f2bf(F_lds[row * 12 + 10])
                     | ((unsigned int)f2bf(F_lds[row * 12 + 11]) << 16);
            }
            *reinterpret_cast<uint2*>(&A_lds[row * LDA + d]) = pk;
        }
    }

    // prefetch first two B k-slices; latency overlaps the gather tail
    LOAD_B(b0, 0);
    LOAD_B(b1, 1);
    __syncthreads();

    // ---- MFMA GEMM: 4 waves as 1M x 4N, wave tile 64 x 96, reg-dbuf B ----
    f32x4 acc[4][6];
    #pragma unroll
    for (int mf = 0; mf < 4; ++mf)
        #pragma unroll
        for (int nf = 0; nf < 6; ++nf)
            acc[mf][nf] = (f32x4){0.f, 0.f, 0.f, 0.f};

    const int arow0 = l15 * LDA + lq * 8;

#define GEMM_STEP(bank, ksl) {                                                   \
    bf16x8 a0 = *reinterpret_cast<const bf16x8*>(&A_lds[arow0 + (ksl) * 32]);    \
    bf16x8 a1 = *reinterpret_cast<const bf16x8*>(&A_lds[arow0 + 16 * LDA + (ksl) * 32]); \
    bf16x8 a2 = *reinterpret_cast<const bf16x8*>(&A_lds[arow0 + 32 * LDA + (ksl) * 32]); \
    bf16x8 a3 = *reinterpret_cast<const bf16x8*>(&A_lds[arow0 + 48 * LDA + (ksl) * 32]); \
    _Pragma("unroll")                                                            \
    for (int nf = 0; nf < 6; ++nf) {                                             \
        acc[0][nf] = __builtin_amdgcn_mfma_f32_16x16x32_bf16(a0, bank[nf], acc[0][nf], 0, 0, 0); \
        acc[1][nf] = __builtin_amdgcn_mfma_f32_16x16x32_bf16(a1, bank[nf], acc[1][nf], 0, 0, 0); \
        acc[2][nf] = __builtin_amdgcn_mfma_f32_16x16x32_bf16(a2, bank[nf], acc[2][nf], 0, 0, 0); \
        acc[3][nf] = __builtin_amdgcn_mfma_f32_16x16x32_bf16(a3, bank[nf], acc[3][nf], 0, 0, 0); \
    } }

    GEMM_STEP(b0, 0);
    #pragma unroll
    for (int kp = 0; kp < 4; ++kp) {
        LOAD_B(b0, 2 + 2 * kp);
        GEMM_STEP(b1, 1 + 2 * kp);
        LOAD_B(b1, 3 + 2 * kp);
        GEMM_STEP(b0, 2 + 2 * kp);
    }
    LOAD_B(b0, 10);
    GEMM_STEP(b1, 9);
    GEMM_STEP(b0, 10);

    // ---- epilogue: +bias, leaky_relu; LDS transpose (2 chunks of 32 rows) ----
    float bv[6];
    #pragma unroll
    for (int nf = 0; nf < 6; ++nf) {
        int col = wn * 96 + nf * 16 + l15;
        bv[nf] = (col < DDIM) ? bias[col] : 0.f;
    }

    float* T_lds = reinterpret_cast<float*>(A_lds);         // 32*322*4 = 41.2 KB <= 45 KB
    float* outp = out + mbase * DDIM;
    const int CH4 = 32 * DDIM / 4;                          // 2576 f32x4 per 32-row chunk

    #pragma unroll
    for (int h = 0; h < 2; ++h) {
        __syncthreads();                                    // A_lds / prev chunk reads done
        #pragma unroll
        for (int m2 = 0; m2 < 2; ++m2) {
            const int mf = h * 2 + m2;
            #pragma unroll
            for (int nf = 0; nf < 6; ++nf) {
                int col = wn * 96 + nf * 16 + l15;
                if (col < DDIM) {
                    #pragma unroll
                    for (int r = 0; r < 4; ++r) {
                        float x = acc[mf][nf][r] + bv[nf];
                        x = (x > 0.f) ? x : 0.01f * x;
                        T_lds[(m2 * 16 + lq * 4 + r) * DDIM + col] = x;
                    }
                }
            }
        }
        __syncthreads();
        #pragma unroll
        for (int i = 0; i < 11; ++i) {
            int fid = i * 256 + t;
            if (fid < CH4) {
                f32x4 v = *reinterpret_cast<const f32x4*>(&T_lds[fid * 4]);
                __builtin_nontemporal_store(v,
                    reinterpret_cast<f32x4*>(outp + ((long)h * CH4 + fid) * 4));
            }
        }
    }
}

extern "C" void kernel_launch(void* const* d_in, const int* in_sizes, int n_in,
                              void* d_out, int out_size, void* d_ws, size_t ws_size,
                              hipStream_t stream) {
    const float* feature      = (const float*)d_in[0];
    const float* join_tables  = (const float*)d_in[1];
    const float* type_embed   = (const float*)d_in[2];
    const float* column_embed = (const float*)d_in[3];
    const float* W            = (const float*)d_in[4];
    const float* bias         = (const float*)d_in[5];
    float* out = (float*)d_out;
    unsigned short* wb2 = (unsigned short*)d_ws;   // 11*24*512*2 = 270 KB

    hipLaunchKernelGGL(prep_w, dim3((NP * KP + 255) / 256), dim3(256), 0, stream, W, wb2);

    const int nblocks = (BTOT * SQLEN) / MBLK;    // 4096
    hipLaunchKernelGGL(fused_embed_gemm, dim3(nblocks), dim3(256), 0, stream,
                       feature, join_tables, type_embed, column_embed, wb2, bias, out);
}